// Round 4
// baseline (622.428 us; speedup 1.0000x reference)
//
#include <hip/hip_runtime.h>
#include <hip/hip_bf16.h>
#include <stdint.h>

// Problem constants
#define DIM   1024
#define HID   2732
#define HPAD  2752            // HID padded to multiple of 64 (zero-filled)
#define NEXP  8
#define NTOK  4096            // B*S
#define NROW  8192            // NTOK * TOPK

#define G13   (NEXP * HPAD * (DIM / 4))   // ushort4 groups per W1/W3 matrix: 5,636,096
#define GALL  (2 * G13)                   // combined W1+W3 domain
#define G2    (NEXP * DIM * (HPAD / 4))   // ushort4 groups for W2: 5,636,096
#define CONV13_BLKS 2048
#define CONV2_BLKS  1024
#define ROUTE_BLKS  (NTOK / 4)

typedef __attribute__((ext_vector_type(8))) short bf16x8;   // 8 bf16 = 4 VGPRs
typedef __attribute__((ext_vector_type(4))) float f32x4;

__device__ __forceinline__ unsigned short f2bf(float f) {
    union { float f; uint32_t u; } v; v.f = f;
    uint32_t u = v.u;
    return (unsigned short)((u + 0x7FFFu + ((u >> 16) & 1u)) >> 16);  // RNE
}
__device__ __forceinline__ float bf2f(unsigned short h) {
    union { uint32_t u; float f; } v; v.u = ((uint32_t)h) << 16;
    return v.f;
}

#define ASYNC_CP16(g, l) __builtin_amdgcn_global_load_lds( \
    (const __attribute__((address_space(1))) void*)(g), \
    (__attribute__((address_space(3))) void*)(l), 16, 0, 0)

// ---------------- prep1: W1+W3 conversion (grid-stride, ILP=4) + routing --
// blocks [0, CONV13_BLKS)              : W1/W3 f32 -> bf16 padded
// blocks [CONV13_BLKS, +ROUTE_BLKS)    : routing (4 tokens/block, 1 wave each)
__global__ void prep1_kernel(const float* __restrict__ x,  const float* __restrict__ Wg,
                             const float* __restrict__ W1, const float* __restrict__ W3,
                             unsigned short* __restrict__ W1b,
                             unsigned short* __restrict__ W3b,
                             int* __restrict__ counts, int* __restrict__ a_exp,
                             int* __restrict__ a_rank, float* __restrict__ a_w) {
    int b = blockIdx.x;
    if (b < CONV13_BLKS) {
        const uint32_t nthr = CONV13_BLKS * 256;
        uint32_t t0 = (uint32_t)b * 256 + threadIdx.x;
        for (uint32_t g0 = t0; g0 < (uint32_t)GALL; g0 += nthr * 4) {
            float4 v[4]; uint32_t gs[4]; bool ok[4];
#pragma unroll
            for (int k = 0; k < 4; ++k) {
                uint32_t g = g0 + (uint32_t)k * nthr;
                gs[k] = g; ok[k] = g < (uint32_t)GALL;
                v[k] = (float4){0.f, 0.f, 0.f, 0.f};
                if (ok[k]) {
                    uint32_t gg = g < (uint32_t)G13 ? g : g - (uint32_t)G13;
                    const float* src = g < (uint32_t)G13 ? W1 : W3;
                    uint32_t d4 = gg & 255;              // DIM/4 = 256
                    uint32_t rest = gg >> 8;
                    uint32_t hp = rest % HPAD;           // const divisor -> magic mul
                    uint32_t e  = rest / HPAD;
                    if (hp < HID)
                        v[k] = *(const float4*)(src + ((size_t)e * HID + hp) * DIM + d4 * 4);
                }
            }
#pragma unroll
            for (int k = 0; k < 4; ++k) {
                if (ok[k]) {
                    unsigned short* dst = gs[k] < (uint32_t)G13 ? W1b : W3b;
                    uint32_t gg = gs[k] < (uint32_t)G13 ? gs[k] : gs[k] - (uint32_t)G13;
                    ushort4 o;
                    o.x = f2bf(v[k].x); o.y = f2bf(v[k].y);
                    o.z = f2bf(v[k].z); o.w = f2bf(v[k].w);
                    *(ushort4*)(dst + (size_t)gg * 4) = o;
                }
            }
        }
        return;
    }
    b -= CONV13_BLKS;
    // routing: block handles 4 tokens, one wave each
    int wave = threadIdx.x >> 6, lane = threadIdx.x & 63;
    int n = b * 4 + wave;
    const float* xr = x + (size_t)n * DIM + lane * 16;
    float p[NEXP];
#pragma unroll
    for (int e = 0; e < NEXP; ++e) p[e] = 0.f;
#pragma unroll
    for (int i = 0; i < 4; ++i) {
        float4 xv = *(const float4*)(xr + i * 4);
#pragma unroll
        for (int e = 0; e < NEXP; ++e) {
            float4 wv = *(const float4*)(Wg + e * DIM + lane * 16 + i * 4);
            p[e] += xv.x * wv.x + xv.y * wv.y + xv.z * wv.z + xv.w * wv.w;
        }
    }
#pragma unroll
    for (int off = 32; off > 0; off >>= 1)
#pragma unroll
        for (int e = 0; e < NEXP; ++e) p[e] += __shfl_xor(p[e], off);
    if (lane == 0) {
        int i1 = -1, i2 = -1; float m1 = -1e30f, m2 = -1e30f;
#pragma unroll
        for (int e = 0; e < NEXP; ++e) {
            float s = p[e];
            if (s > m1) { m2 = m1; i2 = i1; m1 = s; i1 = e; }
            else if (s > m2) { m2 = s; i2 = e; }
        }
        float e2 = __expf(m2 - m1);           // <= 1
        float inv = 1.f / (1.f + e2);
        int a = n * 2;
        a_exp[a] = i1;  a_w[a] = inv;        a_rank[a] = atomicAdd(&counts[i1], 1);
        a_exp[a+1] = i2; a_w[a+1] = e2 * inv; a_rank[a+1] = atomicAdd(&counts[i2], 1);
    }
}

// ---------------- conv2: W2 f32 [E][DIM][HID] -> bf16 [E][DIM][HPAD] ------
// Runs between gemm1 and gemm2 so W2b is L3-warm for gemm2.
__global__ void conv2_kernel(const float* __restrict__ W2,
                             unsigned short* __restrict__ W2b) {
    const uint32_t nthr = CONV2_BLKS * 256;
    uint32_t t0 = (uint32_t)blockIdx.x * 256 + threadIdx.x;
    for (uint32_t g0 = t0; g0 < (uint32_t)G2; g0 += nthr * 4) {
        float4 v[4]; uint32_t gs[4]; bool ok[4];
#pragma unroll
        for (int k = 0; k < 4; ++k) {
            uint32_t g = g0 + (uint32_t)k * nthr;
            gs[k] = g; ok[k] = g < (uint32_t)G2;
            v[k] = (float4){0.f, 0.f, 0.f, 0.f};
            if (ok[k]) {
                uint32_t h4 = g % (HPAD / 4);            // 688, const divisor
                uint32_t rest = g / (HPAD / 4);
                uint32_t d = rest & (DIM - 1);
                uint32_t e = rest >> 10;
                if (h4 * 4 < HID)
                    v[k] = *(const float4*)(W2 + ((size_t)e * DIM + d) * HID + h4 * 4);
            }
        }
#pragma unroll
        for (int k = 0; k < 4; ++k) {
            if (ok[k]) {
                ushort4 o;
                o.x = f2bf(v[k].x); o.y = f2bf(v[k].y);
                o.z = f2bf(v[k].z); o.w = f2bf(v[k].w);
                *(ushort4*)(W2b + (size_t)gs[k] * 4) = o;
            }
        }
    }
}

// gather x rows into per-expert contiguous bf16 buffer; one block per assignment.
// Expert offsets recomputed inline from counts (8 ints) — no separate scan pass.
__global__ void gather_kernel(const float* __restrict__ x, const int* __restrict__ a_exp,
                              const int* __restrict__ a_rank,
                              const int* __restrict__ counts,
                              unsigned short* __restrict__ XG,
                              int* __restrict__ row_of_a) {
    __shared__ int soff[NEXP];
    if (threadIdx.x == 0) {
        int s = 0;
#pragma unroll
        for (int e = 0; e < NEXP; ++e) { soff[e] = s; s += counts[e]; }
    }
    __syncthreads();
    int a = blockIdx.x, n = a >> 1;
    int row = soff[a_exp[a]] + a_rank[a];
    if (threadIdx.x == 0) row_of_a[a] = row;
    float4 xv = *(const float4*)(x + (size_t)n * DIM + threadIdx.x * 4);
    ushort4 o; o.x = f2bf(xv.x); o.y = f2bf(xv.y); o.z = f2bf(xv.z); o.w = f2bf(xv.w);
    *(ushort4*)(XG + (size_t)row * DIM + threadIdx.x * 4) = o;
}

// ---------------- GEMM1: h = silu(x W1^T) * (x W3^T) ---------------------
// Block tile 128(M) x 64(N), BK=64. 4 waves, each 64x32, dual accumulators.
// LDS XOR-swizzle: global chunk c of tile-row r stored at chunk slot c^(r&7).
__global__ __launch_bounds__(256, 2) void gemm1_kernel(
    const unsigned short* __restrict__ XG,   // [NROW][DIM]
    const unsigned short* __restrict__ W1b,  // [E][HPAD][DIM]
    const unsigned short* __restrict__ W3b,
    const int* __restrict__ counts,
    unsigned short* __restrict__ Hbuf)       // [NROW][HPAD]
{
    const int e = blockIdx.z, mtile = blockIdx.y, ntile = blockIdx.x;
    const int cnt = counts[e];
    if (mtile * 128 >= cnt) return;
    int rowstart = 0;
    for (int i = 0; i < e; ++i) rowstart += counts[i];
    rowstart += mtile * 128;

    __shared__ __align__(16) unsigned short As[128 * 64];
    __shared__ __align__(16) unsigned short B1s[64 * 64];
    __shared__ __align__(16) unsigned short B3s[64 * 64];

    const int tid = threadIdx.x, lane = tid & 63, wave = tid >> 6;
    const int wm = wave >> 1, wn = wave & 1;
    const int quad = lane >> 4;

    const unsigned short* w1e = W1b + (size_t)e * HPAD * DIM;
    const unsigned short* w3e = W3b + (size_t)e * HPAD * DIM;

    const int srow = tid >> 3;
    const int scol = (((tid & 7) ^ (srow & 7)) * 8);
    const unsigned short* ag[4];
#pragma unroll
    for (int r = 0; r < 4; ++r) {
        int grow = rowstart + r * 32 + srow;
        if (grow > NROW - 1) grow = NROW - 1;         // clamp: junk rows discarded at store
        ag[r] = XG + (size_t)grow * DIM + scol;
    }
    const unsigned short* bg1[2]; const unsigned short* bg3[2];
#pragma unroll
    for (int r = 0; r < 2; ++r) {
        int grow = ntile * 64 + r * 32 + srow;
        bg1[r] = w1e + (size_t)grow * DIM + scol;
        bg3[r] = w3e + (size_t)grow * DIM + scol;
    }

    f32x4 acc1[4][2], acc3[4][2];
#pragma unroll
    for (int i = 0; i < 4; ++i)
#pragma unroll
        for (int j = 0; j < 2; ++j) {
            acc1[i][j] = (f32x4){0.f, 0.f, 0.f, 0.f};
            acc3[i][j] = (f32x4){0.f, 0.f, 0.f, 0.f};
        }

    for (int kk = 0; kk < DIM / 64; ++kk) {
        const int k0 = kk * 64;
#pragma unroll
        for (int r = 0; r < 4; ++r)
            ASYNC_CP16(ag[r] + k0, &As[r * 2048 + tid * 8]);
#pragma unroll
        for (int r = 0; r < 2; ++r) {
            ASYNC_CP16(bg1[r] + k0, &B1s[r * 2048 + tid * 8]);
            ASYNC_CP16(bg3[r] + k0, &B3s[r * 2048 + tid * 8]);
        }
        __syncthreads();
#pragma unroll
        for (int ks = 0; ks < 2; ++ks) {
            const int cbase = ks * 4 + quad;            // chunk index 0..7
            bf16x8 af[4], b1f[2], b3f[2];
#pragma unroll
            for (int i = 0; i < 4; ++i) {
                int rl = wm * 64 + i * 16 + (lane & 15);
                af[i] = *(const bf16x8*)&As[rl * 64 + ((cbase ^ (rl & 7)) * 8)];
            }
#pragma unroll
            for (int j = 0; j < 2; ++j) {
                int rl1 = wn * 32 + j * 16 + (lane & 15);
                b1f[j] = *(const bf16x8*)&B1s[rl1 * 64 + ((cbase ^ (rl1 & 7)) * 8)];
                b3f[j] = *(const bf16x8*)&B3s[rl1 * 64 + ((cbase ^ (rl1 & 7)) * 8)];
            }
#pragma unroll
            for (int i = 0; i < 4; ++i)
#pragma unroll
                for (int j = 0; j < 2; ++j) {
                    acc1[i][j] = __builtin_amdgcn_mfma_f32_16x16x32_bf16(af[i], b1f[j], acc1[i][j], 0, 0, 0);
                    acc3[i][j] = __builtin_amdgcn_mfma_f32_16x16x32_bf16(af[i], b3f[j], acc3[i][j], 0, 0, 0);
                }
        }
        __syncthreads();
    }

    int mvalid = cnt - mtile * 128; if (mvalid > 128) mvalid = 128;
#pragma unroll
    for (int i = 0; i < 4; ++i)
#pragma unroll
        for (int r = 0; r < 4; ++r) {
            int rl = wm * 64 + i * 16 + quad * 4 + r;
            if (rl < mvalid) {
                size_t rowg = (size_t)(rowstart + rl);
#pragma unroll
                for (int j = 0; j < 2; ++j) {
                    float v1 = acc1[i][j][r], v3 = acc3[i][j][r];
                    float s = v1 / (1.f + __expf(-v1));      // silu
                    Hbuf[rowg * HPAD + ntile * 64 + wn * 32 + j * 16 + (lane & 15)] = f2bf(s * v3);
                }
            }
        }
}

// ---------------- GEMM2: y = h W2^T -> Ybuf (bf16, unscaled) -------------
// Block tile 128(M) x 128(N), BK=64, K=HPAD. 4 waves, each 64x64.
__global__ __launch_bounds__(256, 2) void gemm2_kernel(
    const unsigned short* __restrict__ Hbuf, // [NROW][HPAD]
    const unsigned short* __restrict__ W2b,  // [E][DIM][HPAD]
    const int* __restrict__ counts,
    unsigned short* __restrict__ Ybuf)       // [NROW][DIM] bf16
{
    const int e = blockIdx.z, mtile = blockIdx.y, ntile = blockIdx.x;
    const int cnt = counts[e];
    if (mtile * 128 >= cnt) return;
    int rowstart = 0;
    for (int i = 0; i < e; ++i) rowstart += counts[i];
    rowstart += mtile * 128;

    __shared__ __align__(16) unsigned short As[128 * 64];
    __shared__ __align__(16) unsigned short Bs[128 * 64];

    const int tid = threadIdx.x, lane = tid & 63, wave = tid >> 6;
    const int wm = wave >> 1, wn = wave & 1;
    const int quad = lane >> 4;

    const unsigned short* w2e = W2b + (size_t)e * DIM * HPAD;
    const int srow = tid >> 3;
    const int scol = (((tid & 7) ^ (srow & 7)) * 8);
    const unsigned short* ag[4]; const unsigned short* bg[4];
#pragma unroll
    for (int r = 0; r < 4; ++r) {
        int grow = rowstart + r * 32 + srow;
        if (grow > NROW - 1) grow = NROW - 1;
        ag[r] = Hbuf + (size_t)grow * HPAD + scol;
        bg[r] = w2e + (size_t)(ntile * 128 + r * 32 + srow) * HPAD + scol;
    }

    f32x4 acc[4][4];
#pragma unroll
    for (int i = 0; i < 4; ++i)
#pragma unroll
        for (int j = 0; j < 4; ++j) acc[i][j] = (f32x4){0.f, 0.f, 0.f, 0.f};

    for (int kk = 0; kk < HPAD / 64; ++kk) {
        const int k0 = kk * 64;
#pragma unroll
        for (int r = 0; r < 4; ++r) {
            ASYNC_CP16(ag[r] + k0, &As[r * 2048 + tid * 8]);
            ASYNC_CP16(bg[r] + k0, &Bs[r * 2048 + tid * 8]);
        }
        __syncthreads();
#pragma unroll
        for (int ks = 0; ks < 2; ++ks) {
            const int cbase = ks * 4 + quad;
            bf16x8 af[4], bf[4];
#pragma unroll
            for (int i = 0; i < 4; ++i) {
                int rla = wm * 64 + i * 16 + (lane & 15);
                int rlb = wn * 64 + i * 16 + (lane & 15);
                af[i] = *(const bf16x8*)&As[rla * 64 + ((cbase ^ (rla & 7)) * 8)];
                bf[i] = *(const bf16x8*)&Bs[rlb * 64 + ((cbase ^ (rlb & 7)) * 8)];
            }
#pragma unroll
            for (int i = 0; i < 4; ++i)
#pragma unroll
                for (int j = 0; j < 4; ++j)
                    acc[i][j] = __builtin_amdgcn_mfma_f32_16x16x32_bf16(af[i], bf[j], acc[i][j], 0, 0, 0);
        }
        __syncthreads();
    }

    int mvalid = cnt - mtile * 128; if (mvalid > 128) mvalid = 128;
#pragma unroll
    for (int i = 0; i < 4; ++i)
#pragma unroll
        for (int r = 0; r < 4; ++r) {
            int rl = wm * 64 + i * 16 + quad * 4 + r;
            if (rl < mvalid) {
                int rowg = rowstart + rl;
                unsigned short* yrow = Ybuf + (size_t)rowg * DIM + ntile * 128 + wn * 64 + (lane & 15);
#pragma unroll
                for (int j = 0; j < 4; ++j)
                    yrow[j * 16] = f2bf(acc[i][j][r]);
            }
        }
}

// ---------------- combine: out[n] = w0*Y[row0] + w1*Y[row1] --------------
__global__ void combine_kernel(const unsigned short* __restrict__ Ybuf,
                               const int* __restrict__ row_of_a,
                               const float* __restrict__ a_w,
                               float* __restrict__ out) {
    int n = blockIdx.x, t = threadIdx.x;                 // 256 threads, DIM/4
    int r0 = row_of_a[2 * n], r1 = row_of_a[2 * n + 1];
    float w0 = a_w[2 * n], w1 = a_w[2 * n + 1];
    ushort4 y0 = *(const ushort4*)(Ybuf + (size_t)r0 * DIM + t * 4);
    ushort4 y1 = *(const ushort4*)(Ybuf + (size_t)r1 * DIM + t * 4);
    float4 o;
    o.x = w0 * bf2f(y0.x) + w1 * bf2f(y1.x);
    o.y = w0 * bf2f(y0.y) + w1 * bf2f(y1.y);
    o.z = w0 * bf2f(y0.z) + w1 * bf2f(y1.z);
    o.w = w0 * bf2f(y0.w) + w1 * bf2f(y1.w);
    *(float4*)(out + (size_t)n * DIM + t * 4) = o;
}

// ---------------- launch -------------------------------------------------
extern "C" void kernel_launch(void* const* d_in, const int* in_sizes, int n_in,
                              void* d_out, int out_size, void* d_ws, size_t ws_size,
                              hipStream_t stream) {
    const float* x  = (const float*)d_in[0];
    const float* Wg = (const float*)d_in[1];
    const float* W1 = (const float*)d_in[2];
    const float* W2 = (const float*)d_in[3];
    const float* W3 = (const float*)d_in[4];
    float* out = (float*)d_out;

    char* ws = (char*)d_ws;
    size_t off = 0;
    auto alloc = [&](size_t bytes) -> void* {
        void* p = ws + off;
        off = (off + bytes + 255) & ~(size_t)255;
        return p;
    };
    int*   counts      = (int*)alloc(NEXP * 4);
    int*   a_exp       = (int*)alloc(NROW * 4);
    int*   a_rank      = (int*)alloc(NROW * 4);
    float* a_w         = (float*)alloc(NROW * 4);
    int*   row_of_a    = (int*)alloc(NROW * 4);
    unsigned short* XG   = (unsigned short*)alloc((size_t)NROW * DIM * 2);
    unsigned short* Hbuf = (unsigned short*)alloc((size_t)NROW * HPAD * 2);
    unsigned short* W1b  = (unsigned short*)alloc((size_t)NEXP * HPAD * DIM * 2);
    unsigned short* W3b  = (unsigned short*)alloc((size_t)NEXP * HPAD * DIM * 2);
    unsigned short* W2b  = (unsigned short*)alloc((size_t)NEXP * DIM * HPAD * 2);
    // Ybuf bf16 (16.8 MB) aliases W1b (45.1 MB): W1b is dead once gemm1 completes.
    unsigned short* Ybuf = (unsigned short*)W1b;

    hipMemsetAsync(counts, 0, NEXP * 4, stream);

    prep1_kernel<<<CONV13_BLKS + ROUTE_BLKS, 256, 0, stream>>>(
        x, Wg, W1, W3, W1b, W3b, counts, a_exp, a_rank, a_w);
    gather_kernel<<<NROW, 256, 0, stream>>>(x, a_exp, a_rank, counts, XG, row_of_a);

    gemm1_kernel<<<dim3(HPAD / 64, 64, NEXP), 256, 0, stream>>>(
        XG, W1b, W3b, counts, Hbuf);
    conv2_kernel<<<CONV2_BLKS, 256, 0, stream>>>(W2, W2b);
    gemm2_kernel<<<dim3(DIM / 128, 64, NEXP), 256, 0, stream>>>(
        Hbuf, W2b, counts, Ybuf);
    combine_kernel<<<NTOK, 256, 0, stream>>>(Ybuf, row_of_a, a_w, out);
}